// Round 1
// baseline (358.989 us; speedup 1.0000x reference)
//
#include <hip/hip_runtime.h>
#include <hip/hip_bf16.h>

#define BB 8
#define CC 256
#define CQD 32
#define NND 4096

typedef __bf16 bf16x8 __attribute__((ext_vector_type(8)));
typedef float f32x4 __attribute__((ext_vector_type(4)));

__device__ __forceinline__ bf16x8 ld_bf16x8(const __bf16* p) {
    return *reinterpret_cast<const bf16x8*>(p);
}

// ---------------- weight conversion ----------------
__global__ __launch_bounds__(256) void prep_weights(
    const float* __restrict__ wq, const float* __restrict__ wk,
    const float* __restrict__ wv, __bf16* __restrict__ wqkb,
    __bf16* __restrict__ wvb) {
    int i = blockIdx.x * 256 + threadIdx.x;
    if (i < 32 * 256) {
        wqkb[i] = (__bf16)wq[i];
    } else if (i < 64 * 256) {
        wqkb[i] = (__bf16)wk[i - 32 * 256];
    } else {
        int j = i - 64 * 256;
        if (j < 256 * 256) wvb[j] = (__bf16)wv[j];
    }
}

// ---------------- x transpose: [b][C][N] f32 -> [b][N][C] bf16 ----------------
__global__ __launch_bounds__(256) void transpose_x(const float* __restrict__ x,
                                                   __bf16* __restrict__ xbT) {
    __shared__ __bf16 tile[64][65];
    int b = blockIdx.z, c0 = blockIdx.y * 64, n0 = blockIdx.x * 64;
    int tx = threadIdx.x & 63;
    int ty = threadIdx.x >> 6;  // 0..3
    const float* src = x + ((size_t)b * CC + c0) * NND + n0;
#pragma unroll
    for (int i = 0; i < 16; i++) {
        int cc = i * 4 + ty;
        tile[cc][tx] = (__bf16)src[(size_t)cc * NND + tx];
    }
    __syncthreads();
    __bf16* dst = xbT + ((size_t)b * NND + n0) * CC + c0;
#pragma unroll
    for (int i = 0; i < 16; i++) {
        int nn = i * 4 + ty;
        dst[(size_t)nn * CC + tx] = tile[tx][nn];
    }
}

// ---------------- q/k projection: out q[b][N][32], k[b][N][32] ----------------
__global__ __launch_bounds__(256) void proj_qk(
    const __bf16* __restrict__ xbT, const __bf16* __restrict__ wqkb,
    const float* __restrict__ bq, const float* __restrict__ bk,
    __bf16* __restrict__ qb, __bf16* __restrict__ kb) {
    const int b = blockIdx.y;
    const int n0 = blockIdx.x * 64;
    const int lane = threadIdx.x & 63;
    const int w = threadIdx.x >> 6;
    const int l15 = lane & 15;
    const int quad = lane >> 4;
    const int n = n0 + w * 16 + l15;
    const __bf16* xrow = xbT + ((size_t)b * NND + n) * CC + quad * 8;
    const f32x4 fzero = {0.f, 0.f, 0.f, 0.f};
    f32x4 acc[4];
#pragma unroll
    for (int i = 0; i < 4; i++) acc[i] = fzero;
#pragma unroll
    for (int k0 = 0; k0 < CC; k0 += 32) {
        bf16x8 bf = ld_bf16x8(xrow + k0);
#pragma unroll
        for (int mt = 0; mt < 4; mt++) {
            bf16x8 af = ld_bf16x8(wqkb + (size_t)(mt * 16 + l15) * CC + k0 + quad * 8);
            acc[mt] = __builtin_amdgcn_mfma_f32_16x16x32_bf16(af, bf, acc[mt], 0, 0, 0);
        }
    }
#pragma unroll
    for (int mt = 0; mt < 4; mt++) {
        const int ob = (mt & 1) * 16 + quad * 4;  // o within 32
        const float* bias = (mt < 2) ? bq : bk;
        __bf16* dst = ((mt < 2) ? qb : kb) + ((size_t)b * NND + n) * CQD + ob;
        union { ushort4 u; __bf16 h[4]; } pk;
#pragma unroll
        for (int r = 0; r < 4; r++) pk.h[r] = (__bf16)(acc[mt][r] + bias[ob + r]);
        *reinterpret_cast<ushort4*>(dst) = pk.u;
    }
}

// ---------------- v projection: out v[b][C][N] bf16 ----------------
__global__ __launch_bounds__(256) void proj_v(const __bf16* __restrict__ xbT,
                                              const __bf16* __restrict__ wvb,
                                              const float* __restrict__ bv,
                                              __bf16* __restrict__ vb) {
    const int b = blockIdx.y;
    const int n0 = blockIdx.x * 64;
    const int lane = threadIdx.x & 63;
    const int w = threadIdx.x >> 6;
    const int l15 = lane & 15;
    const int quad = lane >> 4;
    const int n = n0 + w * 16 + l15;
    const __bf16* xrow = xbT + ((size_t)b * NND + n) * CC + quad * 8;
    const f32x4 fzero = {0.f, 0.f, 0.f, 0.f};
    f32x4 acc[16];
#pragma unroll
    for (int i = 0; i < 16; i++) acc[i] = fzero;
#pragma unroll
    for (int k0 = 0; k0 < CC; k0 += 32) {
        bf16x8 bf = ld_bf16x8(xrow + k0);
#pragma unroll
        for (int mt = 0; mt < 16; mt++) {
            bf16x8 af = ld_bf16x8(wvb + (size_t)(mt * 16 + l15) * CC + k0 + quad * 8);
            acc[mt] = __builtin_amdgcn_mfma_f32_16x16x32_bf16(af, bf, acc[mt], 0, 0, 0);
        }
    }
#pragma unroll
    for (int mt = 0; mt < 16; mt++) {
#pragma unroll
        for (int r = 0; r < 4; r++) {
            int c = mt * 16 + quad * 4 + r;
            vb[((size_t)b * CC + c) * NND + n] = (__bf16)(acc[mt][r] + bv[c]);
        }
    }
}

// ---------------- fused flash attention + epilogue ----------------
// block: 4 waves, 64 i-rows (16 per wave). j-loop in steps of 64.
// LDS: Kt [64][40] bf16, Vt [256][72] bf16, Pt [4][16][72] bf16, alpha/l [64] f32 each
__global__ __launch_bounds__(256) void attention(
    const __bf16* __restrict__ qb, const __bf16* __restrict__ kb,
    const __bf16* __restrict__ vb, const float* __restrict__ gamma,
    const float* __restrict__ x, float* __restrict__ out) {
    __shared__ __align__(16) unsigned char smem[51712];
    __bf16* Kt = (__bf16*)smem;                        // 64*40*2   = 5120
    __bf16* Vt = (__bf16*)(smem + 5120);               // 256*72*2  = 36864
    __bf16* Pt = (__bf16*)(smem + 5120 + 36864);       // 4*16*72*2 = 9216
    float* aL = (float*)(smem + 5120 + 36864 + 9216);  // 64 f32
    float* lL = aL + 64;                               // 64 f32

    const int b = blockIdx.y;
    const int i0 = blockIdx.x * 64;
    const int tid = threadIdx.x;
    const int lane = tid & 63;
    const int w = tid >> 6;
    const int l15 = lane & 15;
    const int quad = lane >> 4;
    const f32x4 fzero = {0.f, 0.f, 0.f, 0.f};

    // Q fragment (A-operand): rows i = i0 + w*16 + l15, k = quad*8..+7
    bf16x8 qfrag = ld_bf16x8(qb + ((size_t)b * NND + i0 + w * 16 + l15) * CQD + quad * 8);

    f32x4 acc[16];  // O^T tiles: acc[ct] -> c = ct*16 + quad*4 + r, i-col = l15
#pragma unroll
    for (int i = 0; i < 16; i++) acc[i] = fzero;
    float m_i[4] = {-1e30f, -1e30f, -1e30f, -1e30f};
    float l_i[4] = {0.f, 0.f, 0.f, 0.f};

    __bf16* Pw = Pt + w * 16 * 72;

    for (int j0 = 0; j0 < NND; j0 += 64) {
        // stage K tile: 64 rows x 32 bf16 (padded stride 40)
        {
            int r = tid >> 2, ch = tid & 3;
            *reinterpret_cast<uint4*>(Kt + r * 40 + ch * 8) =
                *reinterpret_cast<const uint4*>(kb + ((size_t)b * NND + j0 + r) * CQD + ch * 8);
        }
        // stage V tile: 256 rows x 64 bf16 (padded stride 72)
        {
            const __bf16* vs = vb + (size_t)b * CC * NND + j0;
            int ch = tid & 7;
#pragma unroll
            for (int it = 0; it < 8; it++) {
                int c = it * 32 + (tid >> 3);
                *reinterpret_cast<uint4*>(Vt + c * 72 + ch * 8) =
                    *reinterpret_cast<const uint4*>(vs + (size_t)c * NND + ch * 8);
            }
        }
        __syncthreads();

        // S = Q K^T : 16 i x 64 j per wave (4 MFMAs, K-dim = CQ = 32 exactly)
        f32x4 s[4];
#pragma unroll
        for (int jt = 0; jt < 4; jt++) {
            bf16x8 kf = ld_bf16x8(Kt + (jt * 16 + l15) * 40 + quad * 8);
            s[jt] = __builtin_amdgcn_mfma_f32_16x16x32_bf16(qfrag, kf, fzero, 0, 0, 0);
        }

        // online softmax; row i = quad*4 + r, its 16 j-values live in l15 group
        float alpha[4];
#pragma unroll
        for (int r = 0; r < 4; r++) {
            float mx = fmaxf(fmaxf(s[0][r], s[1][r]), fmaxf(s[2][r], s[3][r]));
#pragma unroll
            for (int off = 1; off < 16; off <<= 1) mx = fmaxf(mx, __shfl_xor(mx, off));
            float mnew = fmaxf(m_i[r], mx);
            alpha[r] = __expf(m_i[r] - mnew);
            m_i[r] = mnew;
            float ps = 0.f;
#pragma unroll
            for (int jt = 0; jt < 4; jt++) {
                float p = __expf(s[jt][r] - mnew);
                s[jt][r] = p;
                ps += p;
            }
#pragma unroll
            for (int off = 1; off < 16; off <<= 1) ps += __shfl_xor(ps, off);
            l_i[r] = l_i[r] * alpha[r] + ps;
        }

        // write P (bf16, [16 i][72 stride]) + alpha to LDS
#pragma unroll
        for (int r = 0; r < 4; r++) {
#pragma unroll
            for (int jt = 0; jt < 4; jt++)
                Pw[(quad * 4 + r) * 72 + jt * 16 + l15] = (__bf16)s[jt][r];
        }
        if (l15 == 0) {
#pragma unroll
            for (int r = 0; r < 4; r++) aL[w * 16 + quad * 4 + r] = alpha[r];
        }
        __syncthreads();

        // O^T rescale + accumulate: A = V tile (m=c), B = P (n=i), k = j
        float av = aL[w * 16 + l15];
#pragma unroll
        for (int ct = 0; ct < 16; ct++) acc[ct] *= av;
#pragma unroll
        for (int ks = 0; ks < 2; ks++) {
            bf16x8 pf = ld_bf16x8(Pw + l15 * 72 + ks * 32 + quad * 8);
#pragma unroll
            for (int ct = 0; ct < 16; ct++) {
                bf16x8 vf = ld_bf16x8(Vt + (ct * 16 + l15) * 72 + ks * 32 + quad * 8);
                acc[ct] = __builtin_amdgcn_mfma_f32_16x16x32_bf16(vf, pf, acc[ct], 0, 0, 0);
            }
        }
        __syncthreads();
    }

    // epilogue: out[b][c][i] = gamma * O[c][i]/l[i] + x[b][c][i]
    if (l15 == 0) {
#pragma unroll
        for (int r = 0; r < 4; r++) lL[w * 16 + quad * 4 + r] = l_i[r];
    }
    __syncthreads();
    float linv = 1.0f / lL[w * 16 + l15];
    float g = gamma[0];
    int i = i0 + w * 16 + l15;
#pragma unroll
    for (int ct = 0; ct < 16; ct++) {
#pragma unroll
        for (int r = 0; r < 4; r++) {
            int c = ct * 16 + quad * 4 + r;
            size_t off = ((size_t)b * CC + c) * NND + i;
            out[off] = g * (acc[ct][r] * linv) + x[off];
        }
    }
}

extern "C" void kernel_launch(void* const* d_in, const int* in_sizes, int n_in,
                              void* d_out, int out_size, void* d_ws, size_t ws_size,
                              hipStream_t stream) {
    const float* x = (const float*)d_in[0];
    const float* wq = (const float*)d_in[1];
    const float* bq = (const float*)d_in[2];
    const float* wk = (const float*)d_in[3];
    const float* bk = (const float*)d_in[4];
    const float* wv = (const float*)d_in[5];
    const float* bv = (const float*)d_in[6];
    const float* gamma = (const float*)d_in[7];
    float* out = (float*)d_out;

    char* ws = (char*)d_ws;
    __bf16* xbT = (__bf16*)ws;                      // 8*4096*256*2 = 16777216
    __bf16* qb = (__bf16*)(ws + 16777216);          // 8*4096*32*2  = 2097152
    __bf16* kb = (__bf16*)(ws + 16777216 + 2097152);
    __bf16* vb = (__bf16*)(ws + 16777216 + 2 * 2097152);  // 8*256*4096*2 = 16777216
    __bf16* wqkb = (__bf16*)(ws + 2 * 16777216 + 2 * 2097152);  // 64*256*2 = 32768
    __bf16* wvb = (__bf16*)(ws + 2 * 16777216 + 2 * 2097152 + 32768);  // 256*256*2

    prep_weights<<<320, 256, 0, stream>>>(wq, wk, wv, wqkb, wvb);
    transpose_x<<<dim3(64, 4, 8), 256, 0, stream>>>(x, xbT);
    proj_qk<<<dim3(64, 8), 256, 0, stream>>>(xbT, wqkb, bq, bk, qb, kb);
    proj_v<<<dim3(64, 8), 256, 0, stream>>>(xbT, wvb, bv, vb);
    attention<<<dim3(64, 8), 256, 0, stream>>>(qb, kb, vb, gamma, x, out);
}

// Round 2
// 325.175 us; speedup vs baseline: 1.1040x; 1.1040x over previous
//
#include <hip/hip_runtime.h>
#include <hip/hip_bf16.h>
#include <stdint.h>

#define CC 256
#define CQD 32
#define NND 4096

typedef __bf16 bf16x8 __attribute__((ext_vector_type(8)));
typedef float f32x4 __attribute__((ext_vector_type(4)));

__device__ __forceinline__ bf16x8 ld_bf16x8(const __bf16* p) {
    return *reinterpret_cast<const bf16x8*>(p);
}

// ---------------- weight conversion ----------------
__global__ __launch_bounds__(256) void prep_weights(
    const float* __restrict__ wq, const float* __restrict__ wk,
    const float* __restrict__ wv, __bf16* __restrict__ wqkb,
    __bf16* __restrict__ wvb) {
    int i = blockIdx.x * 256 + threadIdx.x;
    if (i < 32 * 256) {
        wqkb[i] = (__bf16)wq[i];
    } else if (i < 64 * 256) {
        wqkb[i] = (__bf16)wk[i - 32 * 256];
    } else {
        int j = i - 64 * 256;
        if (j < 256 * 256) wvb[j] = (__bf16)wv[j];
    }
}

// ---------------- x transpose: [b][C][N] f32 -> [b][N][C] bf16 ----------------
__global__ __launch_bounds__(256) void transpose_x(const float* __restrict__ x,
                                                   __bf16* __restrict__ xbT) {
    __shared__ __bf16 tile[64][65];
    int b = blockIdx.z, c0 = blockIdx.y * 64, n0 = blockIdx.x * 64;
    int tx = threadIdx.x & 63;
    int ty = threadIdx.x >> 6;  // 0..3
    const float* src = x + ((size_t)b * CC + c0) * NND + n0;
#pragma unroll
    for (int i = 0; i < 16; i++) {
        int cc = i * 4 + ty;
        tile[cc][tx] = (__bf16)src[(size_t)cc * NND + tx];
    }
    __syncthreads();
    __bf16* dst = xbT + ((size_t)b * NND + n0) * CC + c0;
#pragma unroll
    for (int i = 0; i < 16; i++) {
        int nn = i * 4 + ty;
        dst[(size_t)nn * CC + tx] = tile[tx][nn];
    }
}

// ---------------- q/k projection: out q[b][N][32], k[b][N][32] ----------------
__global__ __launch_bounds__(256) void proj_qk(
    const __bf16* __restrict__ xbT, const __bf16* __restrict__ wqkb,
    const float* __restrict__ bq, const float* __restrict__ bk,
    __bf16* __restrict__ qb, __bf16* __restrict__ kb) {
    const int b = blockIdx.y;
    const int n0 = blockIdx.x * 64;
    const int lane = threadIdx.x & 63;
    const int w = threadIdx.x >> 6;
    const int l15 = lane & 15;
    const int quad = lane >> 4;
    const int n = n0 + w * 16 + l15;
    const __bf16* xrow = xbT + ((size_t)b * NND + n) * CC + quad * 8;
    const f32x4 fzero = {0.f, 0.f, 0.f, 0.f};
    f32x4 acc[4];
#pragma unroll
    for (int i = 0; i < 4; i++) acc[i] = fzero;
#pragma unroll
    for (int k0 = 0; k0 < CC; k0 += 32) {
        bf16x8 bf = ld_bf16x8(xrow + k0);
#pragma unroll
        for (int mt = 0; mt < 4; mt++) {
            bf16x8 af = ld_bf16x8(wqkb + (size_t)(mt * 16 + l15) * CC + k0 + quad * 8);
            acc[mt] = __builtin_amdgcn_mfma_f32_16x16x32_bf16(af, bf, acc[mt], 0, 0, 0);
        }
    }
#pragma unroll
    for (int mt = 0; mt < 4; mt++) {
        const int ob = (mt & 1) * 16 + quad * 4;  // o within 32
        const float* bias = (mt < 2) ? bq : bk;
        __bf16* dst = ((mt < 2) ? qb : kb) + ((size_t)b * NND + n) * CQD + ob;
        union { ushort4 u; __bf16 h[4]; } pk;
#pragma unroll
        for (int r = 0; r < 4; r++) pk.h[r] = (__bf16)(acc[mt][r] + bias[ob + r]);
        *reinterpret_cast<ushort4*>(dst) = pk.u;
    }
}

// ---------------- v projection: out v[b][C][N] bf16 ----------------
__global__ __launch_bounds__(256) void proj_v(const __bf16* __restrict__ xbT,
                                              const __bf16* __restrict__ wvb,
                                              const float* __restrict__ bv,
                                              __bf16* __restrict__ vb) {
    const int b = blockIdx.y;
    const int n0 = blockIdx.x * 64;
    const int lane = threadIdx.x & 63;
    const int w = threadIdx.x >> 6;
    const int l15 = lane & 15;
    const int quad = lane >> 4;
    const int n = n0 + w * 16 + l15;
    const __bf16* xrow = xbT + ((size_t)b * NND + n) * CC + quad * 8;
    const f32x4 fzero = {0.f, 0.f, 0.f, 0.f};
    f32x4 acc[16];
#pragma unroll
    for (int i = 0; i < 16; i++) acc[i] = fzero;
#pragma unroll
    for (int k0 = 0; k0 < CC; k0 += 32) {
        bf16x8 bf = ld_bf16x8(xrow + k0);
#pragma unroll
        for (int mt = 0; mt < 16; mt++) {
            bf16x8 af = ld_bf16x8(wvb + (size_t)(mt * 16 + l15) * CC + k0 + quad * 8);
            acc[mt] = __builtin_amdgcn_mfma_f32_16x16x32_bf16(af, bf, acc[mt], 0, 0, 0);
        }
    }
#pragma unroll
    for (int mt = 0; mt < 16; mt++) {
#pragma unroll
        for (int r = 0; r < 4; r++) {
            int c = mt * 16 + quad * 4 + r;
            vb[((size_t)b * CC + c) * NND + n] = (__bf16)(acc[mt][r] + bv[c]);
        }
    }
}

// ---------------- fused flash attention + epilogue ----------------
// TI=128 i/block, 4 waves. S^T formulation (A=K, B=Q): per-lane softmax rows.
// PV c-split: wave w owns c in [w*64, w*64+64), all 8 i-tiles.
// V staged via global_load_lds (width=16) into XOR-swizzled LDS (swizzle on
// the global source address side so lane-order-contiguous LDS dest holds the
// swizzled layout). K fragments direct from global, prefetched 1 step ahead.
// grid = 256 blocks = 1/CU; LDS 52 KB; 2 barriers/j-step.
__global__ __launch_bounds__(256, 1) void attention(
    const __bf16* __restrict__ qb, const __bf16* __restrict__ kb,
    const __bf16* __restrict__ vb, const float* __restrict__ gamma,
    const float* __restrict__ x, float* __restrict__ out) {
    __shared__ __align__(16) __bf16 Vt[CC * 64];   // 32768 B, swizzled rows
    __shared__ __align__(16) __bf16 Pt[128 * 72];  // 18432 B, [i][j] stride 72
    __shared__ float aL[128];
    __shared__ float lL[128];

    const int b = blockIdx.y;
    const int i0 = blockIdx.x * 128;
    const int tid = threadIdx.x;
    const int w = tid >> 6;
    const int lane = tid & 63;
    const int l15 = lane & 15;
    const int quad = lane >> 4;
    const f32x4 fzero = {0.f, 0.f, 0.f, 0.f};

    // Q fragments (B-operand): n=i = i0 + w*32 + t2*16 + l15, k(c) = quad*8..
    bf16x8 qf[2];
#pragma unroll
    for (int t2 = 0; t2 < 2; t2++)
        qf[t2] = ld_bf16x8(qb + ((size_t)b * NND + i0 + w * 32 + t2 * 16 + l15) * CQD + quad * 8);

    // K fragments (A-operand) for j0 = 0: m=j = jt*16 + l15
    bf16x8 kf[4];
#pragma unroll
    for (int jt = 0; jt < 4; jt++)
        kf[jt] = ld_bf16x8(kb + ((size_t)b * NND + jt * 16 + l15) * CQD + quad * 8);

    // global_load_lds source: lane -> row w*64 + (lane>>3), chunk swizzled
    const int vrow = lane >> 3;
    const int vswz = ((lane & 7) ^ vrow) * 8;
    const __bf16* vsrc = vb + ((size_t)(b * CC + w * 64 + vrow)) * NND + vswz;
    __bf16* vdstb = &Vt[(w * 64) * 64];  // wave-uniform base; +lane*16B by HW

    f32x4 acc[4][8];  // [ct][it]: c = w*64+ct*16+quad*4+r, i = it*16+l15
#pragma unroll
    for (int ct = 0; ct < 4; ct++)
#pragma unroll
        for (int it = 0; it < 8; it++) acc[ct][it] = fzero;
    float m_i[2] = {-1e30f, -1e30f};
    float l_i[2] = {0.f, 0.f};
    const int swz = (l15 & 7) * 8;

    for (int j0 = 0; j0 < NND; j0 += 64) {
        __syncthreads();  // barrier 1: prev PV done -> safe to overwrite Vt/Pt
        // stage V(j0): 8 x global_load_lds width=16 per wave (own c-slice)
#pragma unroll
        for (int t = 0; t < 8; t++) {
            __builtin_amdgcn_global_load_lds(
                (const __attribute__((address_space(1))) void*)(vsrc + (size_t)t * 8 * NND + j0),
                (__attribute__((address_space(3))) void*)(vdstb + t * 8 * 64), 16, 0, 0);
        }
        // S^T = K Q^T : col = i (l15), row = j (quad*4+r)
        f32x4 sT[2][4];
#pragma unroll
        for (int t2 = 0; t2 < 2; t2++)
#pragma unroll
            for (int jt = 0; jt < 4; jt++)
                sT[t2][jt] = __builtin_amdgcn_mfma_f32_16x16x32_bf16(kf[jt], qf[t2], fzero, 0, 0, 0);
        // prefetch K(j0+64) into regs (consumed next iter)
        if (j0 + 64 < NND) {
#pragma unroll
            for (int jt = 0; jt < 4; jt++)
                kf[jt] = ld_bf16x8(kb + ((size_t)b * NND + j0 + 64 + jt * 16 + l15) * CQD + quad * 8);
        }
        // online softmax (per-lane rows) + P pack/write
#pragma unroll
        for (int t2 = 0; t2 < 2; t2++) {
            float mx = -1e30f;
#pragma unroll
            for (int jt = 0; jt < 4; jt++)
#pragma unroll
                for (int r = 0; r < 4; r++) mx = fmaxf(mx, sT[t2][jt][r]);
            mx = fmaxf(mx, __shfl_xor(mx, 16));
            mx = fmaxf(mx, __shfl_xor(mx, 32));
            float mnew = fmaxf(m_i[t2], mx);
            float alpha = __expf(m_i[t2] - mnew);
            m_i[t2] = mnew;
            float ps = 0.f;
#pragma unroll
            for (int jt = 0; jt < 4; jt++) {
                union { ushort4 u4; __bf16 h[4]; } pk;
#pragma unroll
                for (int r = 0; r < 4; r++) {
                    float p = __expf(sT[t2][jt][r] - mnew);
                    ps += p;
                    pk.h[r] = (__bf16)p;
                }
                *reinterpret_cast<ushort4*>(
                    &Pt[(w * 32 + t2 * 16 + l15) * 72 + jt * 16 + quad * 4]) = pk.u4;
            }
            ps += __shfl_xor(ps, 16);
            ps += __shfl_xor(ps, 32);
            l_i[t2] = l_i[t2] * alpha + ps;
            if (quad == 0) aL[w * 32 + t2 * 16 + l15] = alpha;
        }
        __syncthreads();  // barrier 2: drains gll (V ready) + P/alpha visible
        // rescale
        float av[8];
#pragma unroll
        for (int it = 0; it < 8; it++) av[it] = aL[it * 16 + l15];
#pragma unroll
        for (int ct = 0; ct < 4; ct++)
#pragma unroll
            for (int it = 0; it < 8; it++) acc[ct][it] *= av[it];
        // PV: A = V (m=c), B = P (n=i); each vf feeds 8 MFMAs
#pragma unroll
        for (int ks = 0; ks < 2; ks++) {
            bf16x8 vf[4];
#pragma unroll
            for (int ct = 0; ct < 4; ct++) {
                int cr = w * 64 + ct * 16 + l15;
                vf[ct] = ld_bf16x8(&Vt[cr * 64 + ((ks * 32 + quad * 8) ^ swz)]);
            }
#pragma unroll
            for (int it = 0; it < 8; it++) {
                bf16x8 pf = ld_bf16x8(&Pt[(it * 16 + l15) * 72 + ks * 32 + quad * 8]);
#pragma unroll
                for (int ct = 0; ct < 4; ct++)
                    acc[ct][it] = __builtin_amdgcn_mfma_f32_16x16x32_bf16(vf[ct], pf, acc[ct][it], 0, 0, 0);
            }
        }
    }
    // epilogue: out = gamma * O / l + x
    __syncthreads();
    if (quad == 0) {
        lL[w * 32 + l15] = l_i[0];
        lL[w * 32 + 16 + l15] = l_i[1];
    }
    __syncthreads();
    float linv[8];
#pragma unroll
    for (int it = 0; it < 8; it++) linv[it] = 1.0f / lL[it * 16 + l15];
    float g = gamma[0];
#pragma unroll
    for (int ct = 0; ct < 4; ct++) {
#pragma unroll
        for (int it = 0; it < 8; it++) {
#pragma unroll
            for (int r = 0; r < 4; r++) {
                int c = w * 64 + ct * 16 + quad * 4 + r;
                int i = i0 + it * 16 + l15;
                size_t off = ((size_t)b * CC + c) * NND + i;
                out[off] = g * (acc[ct][it][r] * linv[it]) + x[off];
            }
        }
    }
}

extern "C" void kernel_launch(void* const* d_in, const int* in_sizes, int n_in,
                              void* d_out, int out_size, void* d_ws, size_t ws_size,
                              hipStream_t stream) {
    const float* x = (const float*)d_in[0];
    const float* wq = (const float*)d_in[1];
    const float* bq = (const float*)d_in[2];
    const float* wk = (const float*)d_in[3];
    const float* bk = (const float*)d_in[4];
    const float* wv = (const float*)d_in[5];
    const float* bv = (const float*)d_in[6];
    const float* gamma = (const float*)d_in[7];
    float* out = (float*)d_out;

    char* ws = (char*)d_ws;
    __bf16* xbT = (__bf16*)ws;                      // 8*4096*256*2 = 16777216
    __bf16* qb = (__bf16*)(ws + 16777216);          // 8*4096*32*2  = 2097152
    __bf16* kb = (__bf16*)(ws + 16777216 + 2097152);
    __bf16* vb = (__bf16*)(ws + 16777216 + 2 * 2097152);  // 8*256*4096*2 = 16777216
    __bf16* wqkb = (__bf16*)(ws + 2 * 16777216 + 2 * 2097152);  // 64*256*2 = 32768
    __bf16* wvb = (__bf16*)(ws + 2 * 16777216 + 2 * 2097152 + 32768);  // 256*256*2

    prep_weights<<<320, 256, 0, stream>>>(wq, wk, wv, wqkb, wvb);
    transpose_x<<<dim3(64, 4, 8), 256, 0, stream>>>(x, xbT);
    proj_qk<<<dim3(64, 8), 256, 0, stream>>>(xbT, wqkb, bq, bk, qb, kb);
    proj_v<<<dim3(64, 8), 256, 0, stream>>>(xbT, wvb, bv, vb);
    attention<<<dim3(32, 8), 256, 0, stream>>>(qb, kb, vb, gamma, x, out);
}

// Round 3
// 263.815 us; speedup vs baseline: 1.3608x; 1.2326x over previous
//
#include <hip/hip_runtime.h>
#include <hip/hip_bf16.h>
#include <stdint.h>

#define CC 256
#define CQD 32
#define NND 4096

typedef __bf16 bf16x8 __attribute__((ext_vector_type(8)));
typedef float f32x4 __attribute__((ext_vector_type(4)));

__device__ __forceinline__ bf16x8 ld_bf16x8(const __bf16* p) {
    return *reinterpret_cast<const bf16x8*>(p);
}

// ---------------- weight conversion ----------------
__global__ __launch_bounds__(256) void prep_weights(
    const float* __restrict__ wq, const float* __restrict__ wk,
    const float* __restrict__ wv, __bf16* __restrict__ wqkb,
    __bf16* __restrict__ wvb) {
    int i = blockIdx.x * 256 + threadIdx.x;
    if (i < 32 * 256) {
        wqkb[i] = (__bf16)wq[i];
    } else if (i < 64 * 256) {
        wqkb[i] = (__bf16)wk[i - 32 * 256];
    } else {
        int j = i - 64 * 256;
        if (j < 256 * 256) wvb[j] = (__bf16)wv[j];
    }
}

// ---------------- x transpose: [b][C][N] f32 -> [b][N][C] bf16 ----------------
__global__ __launch_bounds__(256) void transpose_x(const float* __restrict__ x,
                                                   __bf16* __restrict__ xbT) {
    __shared__ __bf16 tile[64][65];
    int b = blockIdx.z, c0 = blockIdx.y * 64, n0 = blockIdx.x * 64;
    int tx = threadIdx.x & 63;
    int ty = threadIdx.x >> 6;  // 0..3
    const float* src = x + ((size_t)b * CC + c0) * NND + n0;
#pragma unroll
    for (int i = 0; i < 16; i++) {
        int cc = i * 4 + ty;
        tile[cc][tx] = (__bf16)src[(size_t)cc * NND + tx];
    }
    __syncthreads();
    __bf16* dst = xbT + ((size_t)b * NND + n0) * CC + c0;
#pragma unroll
    for (int i = 0; i < 16; i++) {
        int nn = i * 4 + ty;
        dst[(size_t)nn * CC + tx] = tile[tx][nn];
    }
}

// ---------------- q/k projection: out q[b][N][32], k[b][N][32] ----------------
__global__ __launch_bounds__(256) void proj_qk(
    const __bf16* __restrict__ xbT, const __bf16* __restrict__ wqkb,
    const float* __restrict__ bq, const float* __restrict__ bk,
    __bf16* __restrict__ qb, __bf16* __restrict__ kb) {
    const int b = blockIdx.y;
    const int n0 = blockIdx.x * 64;
    const int lane = threadIdx.x & 63;
    const int w = threadIdx.x >> 6;
    const int l15 = lane & 15;
    const int quad = lane >> 4;
    const int n = n0 + w * 16 + l15;
    const __bf16* xrow = xbT + ((size_t)b * NND + n) * CC + quad * 8;
    const f32x4 fzero = {0.f, 0.f, 0.f, 0.f};
    f32x4 acc[4];
#pragma unroll
    for (int i = 0; i < 4; i++) acc[i] = fzero;
#pragma unroll
    for (int k0 = 0; k0 < CC; k0 += 32) {
        bf16x8 bf = ld_bf16x8(xrow + k0);
#pragma unroll
        for (int mt = 0; mt < 4; mt++) {
            bf16x8 af = ld_bf16x8(wqkb + (size_t)(mt * 16 + l15) * CC + k0 + quad * 8);
            acc[mt] = __builtin_amdgcn_mfma_f32_16x16x32_bf16(af, bf, acc[mt], 0, 0, 0);
        }
    }
#pragma unroll
    for (int mt = 0; mt < 4; mt++) {
        const int ob = (mt & 1) * 16 + quad * 4;  // o within 32
        const float* bias = (mt < 2) ? bq : bk;
        __bf16* dst = ((mt < 2) ? qb : kb) + ((size_t)b * NND + n) * CQD + ob;
        union { ushort4 u; __bf16 h[4]; } pk;
#pragma unroll
        for (int r = 0; r < 4; r++) pk.h[r] = (__bf16)(acc[mt][r] + bias[ob + r]);
        *reinterpret_cast<ushort4*>(dst) = pk.u;
    }
}

// ---------------- v projection: out v[b][C][N] bf16 ----------------
__global__ __launch_bounds__(256) void proj_v(const __bf16* __restrict__ xbT,
                                              const __bf16* __restrict__ wvb,
                                              const float* __restrict__ bv,
                                              __bf16* __restrict__ vb) {
    const int b = blockIdx.y;
    const int n0 = blockIdx.x * 64;
    const int lane = threadIdx.x & 63;
    const int w = threadIdx.x >> 6;
    const int l15 = lane & 15;
    const int quad = lane >> 4;
    const int n = n0 + w * 16 + l15;
    const __bf16* xrow = xbT + ((size_t)b * NND + n) * CC + quad * 8;
    const f32x4 fzero = {0.f, 0.f, 0.f, 0.f};
    f32x4 acc[16];
#pragma unroll
    for (int i = 0; i < 16; i++) acc[i] = fzero;
#pragma unroll
    for (int k0 = 0; k0 < CC; k0 += 32) {
        bf16x8 bf = ld_bf16x8(xrow + k0);
#pragma unroll
        for (int mt = 0; mt < 16; mt++) {
            bf16x8 af = ld_bf16x8(wvb + (size_t)(mt * 16 + l15) * CC + k0 + quad * 8);
            acc[mt] = __builtin_amdgcn_mfma_f32_16x16x32_bf16(af, bf, acc[mt], 0, 0, 0);
        }
    }
#pragma unroll
    for (int mt = 0; mt < 16; mt++) {
#pragma unroll
        for (int r = 0; r < 4; r++) {
            int c = mt * 16 + quad * 4 + r;
            vb[((size_t)b * CC + c) * NND + n] = (__bf16)(acc[mt][r] + bv[c]);
        }
    }
}

// ---------------- fused flash attention + epilogue ----------------
// TI=64 i/block, 4 waves, 2 blocks/CU (grid 512, launch_bounds(256,2)).
// S^T formulation (A=K, B=Q): per-lane softmax rows (wave w owns i-tile w).
// PV c-split: wave w owns c in [w*64, w*64+64), all 4 i-tiles.
// V staged via global_load_lds width=16 into XOR-swizzled LDS; K fragments
// direct from global (L1-shared across the 4 waves), prefetched 1 step ahead.
// 2 blocks/CU interleave softmax-VALU and PV-LDS/MFMA phases.
__global__ __launch_bounds__(256, 2) void attention(
    const __bf16* __restrict__ qb, const __bf16* __restrict__ kb,
    const __bf16* __restrict__ vb, const float* __restrict__ gamma,
    const float* __restrict__ x, float* __restrict__ out) {
    __shared__ __align__(16) __bf16 Vt[CC * 64];  // 32768 B, swizzled rows
    __shared__ __align__(16) __bf16 Pt[64 * 72];  // 9216 B, [i][j] stride 72
    __shared__ float aL[64];
    __shared__ float lL[64];

    const int b = blockIdx.y;
    const int i0 = blockIdx.x * 64;
    const int tid = threadIdx.x;
    const int w = tid >> 6;
    const int lane = tid & 63;
    const int l15 = lane & 15;
    const int quad = lane >> 4;
    const f32x4 fzero = {0.f, 0.f, 0.f, 0.f};

    // Q fragment (B-operand): n=i = i0 + w*16 + l15, k(c) = quad*8..
    bf16x8 qf = ld_bf16x8(qb + ((size_t)b * NND + i0 + w * 16 + l15) * CQD + quad * 8);

    // K fragments (A-operand) for j0 = 0: m=j = jt*16 + l15
    bf16x8 kf[4];
#pragma unroll
    for (int jt = 0; jt < 4; jt++)
        kf[jt] = ld_bf16x8(kb + ((size_t)b * NND + jt * 16 + l15) * CQD + quad * 8);

    // global_load_lds source: lane -> row w*64 + (lane>>3), chunk swizzled
    const int vrow = lane >> 3;
    const int vswz = ((lane & 7) ^ vrow) * 8;
    const __bf16* vsrc = vb + ((size_t)(b * CC + w * 64 + vrow)) * NND + vswz;
    __bf16* vdstb = &Vt[(w * 64) * 64];  // wave-uniform base; +lane*16B by HW

    f32x4 acc[4][4];  // [ct][it]: c = w*64+ct*16+quad*4+r, i = it*16+l15
#pragma unroll
    for (int ct = 0; ct < 4; ct++)
#pragma unroll
        for (int it = 0; it < 4; it++) acc[ct][it] = fzero;
    float m_i = -1e30f;
    float l_i = 0.f;
    const int swz = (l15 & 7) * 8;

    for (int j0 = 0; j0 < NND; j0 += 64) {
        __syncthreads();  // barrier 1: prev PV done -> safe to overwrite Vt/Pt
        // stage V(j0): 8 x global_load_lds width=16 per wave (own c-slice)
#pragma unroll
        for (int t = 0; t < 8; t++) {
            __builtin_amdgcn_global_load_lds(
                (const __attribute__((address_space(1))) void*)(vsrc + (size_t)t * 8 * NND + j0),
                (__attribute__((address_space(3))) void*)(vdstb + t * 8 * 64), 16, 0, 0);
        }
        // S^T = K Q^T : col = i (l15), row = j (jt*16 + quad*4 + r)
        f32x4 sT[4];
#pragma unroll
        for (int jt = 0; jt < 4; jt++)
            sT[jt] = __builtin_amdgcn_mfma_f32_16x16x32_bf16(kf[jt], qf, fzero, 0, 0, 0);
        // prefetch K(j0+64) into regs (consumed next iter)
        if (j0 + 64 < NND) {
#pragma unroll
            for (int jt = 0; jt < 4; jt++)
                kf[jt] = ld_bf16x8(kb + ((size_t)b * NND + j0 + 64 + jt * 16 + l15) * CQD + quad * 8);
        }
        // online softmax (per-lane row i = i0 + w*16 + l15) + P pack/write
        {
            float mx = -1e30f;
#pragma unroll
            for (int jt = 0; jt < 4; jt++)
#pragma unroll
                for (int r = 0; r < 4; r++) mx = fmaxf(mx, sT[jt][r]);
            mx = fmaxf(mx, __shfl_xor(mx, 16));
            mx = fmaxf(mx, __shfl_xor(mx, 32));
            float mnew = fmaxf(m_i, mx);
            float alpha = __expf(m_i - mnew);
            m_i = mnew;
            float ps = 0.f;
#pragma unroll
            for (int jt = 0; jt < 4; jt++) {
                union { ushort4 u4; __bf16 h[4]; } pk;
#pragma unroll
                for (int r = 0; r < 4; r++) {
                    float p = __expf(sT[jt][r] - mnew);
                    ps += p;
                    pk.h[r] = (__bf16)p;
                }
                *reinterpret_cast<ushort4*>(
                    &Pt[(w * 16 + l15) * 72 + jt * 16 + quad * 4]) = pk.u4;
            }
            ps += __shfl_xor(ps, 16);
            ps += __shfl_xor(ps, 32);
            l_i = l_i * alpha + ps;
            if (quad == 0) aL[w * 16 + l15] = alpha;
        }
        __syncthreads();  // barrier 2: drains gll (V ready) + P/alpha visible
        // rescale
        float av[4];
#pragma unroll
        for (int it = 0; it < 4; it++) av[it] = aL[it * 16 + l15];
#pragma unroll
        for (int ct = 0; ct < 4; ct++)
#pragma unroll
            for (int it = 0; it < 4; it++) acc[ct][it] *= av[it];
        // PV: A = V (m=c), B = P (n=i); each vf feeds 4 MFMAs
#pragma unroll
        for (int ks = 0; ks < 2; ks++) {
            bf16x8 vf[4];
#pragma unroll
            for (int ct = 0; ct < 4; ct++) {
                int cr = w * 64 + ct * 16 + l15;
                vf[ct] = ld_bf16x8(&Vt[cr * 64 + ((ks * 32 + quad * 8) ^ swz)]);
            }
#pragma unroll
            for (int it = 0; it < 4; it++) {
                bf16x8 pf = ld_bf16x8(&Pt[(it * 16 + l15) * 72 + ks * 32 + quad * 8]);
#pragma unroll
                for (int ct = 0; ct < 4; ct++)
                    acc[ct][it] = __builtin_amdgcn_mfma_f32_16x16x32_bf16(vf[ct], pf, acc[ct][it], 0, 0, 0);
            }
        }
    }
    // epilogue: out = gamma * O / l + x
    __syncthreads();
    if (quad == 0) lL[w * 16 + l15] = l_i;
    __syncthreads();
    float linv[4];
#pragma unroll
    for (int it = 0; it < 4; it++) linv[it] = 1.0f / lL[it * 16 + l15];
    float g = gamma[0];
#pragma unroll
    for (int ct = 0; ct < 4; ct++) {
#pragma unroll
        for (int it = 0; it < 4; it++) {
#pragma unroll
            for (int r = 0; r < 4; r++) {
                int c = w * 64 + ct * 16 + quad * 4 + r;
                int i = i0 + it * 16 + l15;
                size_t off = ((size_t)b * CC + c) * NND + i;
                out[off] = g * (acc[ct][it][r] * linv[it]) + x[off];
            }
        }
    }
}

extern "C" void kernel_launch(void* const* d_in, const int* in_sizes, int n_in,
                              void* d_out, int out_size, void* d_ws, size_t ws_size,
                              hipStream_t stream) {
    const float* x = (const float*)d_in[0];
    const float* wq = (const float*)d_in[1];
    const float* bq = (const float*)d_in[2];
    const float* wk = (const float*)d_in[3];
    const float* bk = (const float*)d_in[4];
    const float* wv = (const float*)d_in[5];
    const float* bv = (const float*)d_in[6];
    const float* gamma = (const float*)d_in[7];
    float* out = (float*)d_out;

    char* ws = (char*)d_ws;
    __bf16* xbT = (__bf16*)ws;                      // 8*4096*256*2 = 16777216
    __bf16* qb = (__bf16*)(ws + 16777216);          // 8*4096*32*2  = 2097152
    __bf16* kb = (__bf16*)(ws + 16777216 + 2097152);
    __bf16* vb = (__bf16*)(ws + 16777216 + 2 * 2097152);  // 8*256*4096*2 = 16777216
    __bf16* wqkb = (__bf16*)(ws + 2 * 16777216 + 2 * 2097152);  // 64*256*2 = 32768
    __bf16* wvb = (__bf16*)(ws + 2 * 16777216 + 2 * 2097152 + 32768);  // 256*256*2

    prep_weights<<<320, 256, 0, stream>>>(wq, wk, wv, wqkb, wvb);
    transpose_x<<<dim3(64, 4, 8), 256, 0, stream>>>(x, xbT);
    proj_qk<<<dim3(64, 8), 256, 0, stream>>>(xbT, wqkb, bq, bk, qb, kb);
    proj_v<<<dim3(64, 8), 256, 0, stream>>>(xbT, wvb, bv, vb);
    attention<<<dim3(64, 8), 256, 0, stream>>>(qb, kb, vb, gamma, x, out);
}